// Round 23
// baseline (133.546 us; speedup 1.0000x reference)
//
#include <hip/hip_runtime.h>
#include <stdint.h>

#define S 4
#define B 64
#define D 32
#define N 784
#define P 2
#define L 10
#define HALF 392
#define NSTEP 391
#define NPAIR 196              // 195 real pairs + 1 leftover single site
#define SLICE 4096             // floats per pair slice: 4 combos * 32*32 (16 KB)

typedef float f4 __attribute__((ext_vector_type(4)));
typedef float f2 __attribute__((ext_vector_type(2)));

__device__ __forceinline__ float bcast(float v, int lane) {
    return __uint_as_float(__builtin_amdgcn_readlane(__float_as_uint(v), lane));
}

// ---------------- precompute: pair matrices + weight table ----------------
// W layout (per stream,t): float4-chunk index (bb*8+qq)*64 + c2*32+f,
// chunk holds content[c = c2+2*bb][f][e = 4*qq + r].
// left:  content[c][f][e] = P_c[e][f];  right: content[c][f][e] = Q_c[f][e].
// wtab layout: [(side*64 + b)*NPAIR + t] (float4).
__global__ __launch_bounds__(256) void pair_kernel(
    const float* __restrict__ A_left, const float* __restrict__ A_right,
    const float* __restrict__ x,
    float* __restrict__ Wbuf, float* __restrict__ wtab)
{
    const int stream = blockIdx.x;      // 0..7 -> linear_id % 8 == stream (XCD pin)
    const int t      = blockIdx.y;      // 0..195
    const int side   = stream >> 2, s = stream & 3;
    __shared__ float sA[2048], sB[2048];
    const int tid = threadIdx.x;
    const bool leftover = (t == 195);

    const float* As = (side ? A_right : A_left) + (size_t)s * (NSTEP * 2048);
    int ia, ib;
    if (side == 0) { ia = 2 * t; ib = 2 * t + 1; }
    else           { ia = 389 - 2 * t; ib = 390 - 2 * t; }
    if (leftover)  { ia = side ? 0 : 390; ib = ia; }

    const float4* ga = (const float4*)(As + (size_t)ia * 2048);
    const float4* gb = (const float4*)(As + (size_t)ib * 2048);
    ((float4*)sA)[tid] = ga[tid]; ((float4*)sA)[tid + 256] = ga[tid + 256];
    ((float4*)sB)[tid] = gb[tid]; ((float4*)sB)[tid + 256] = gb[tid + 256];
    __syncthreads();

    const int c = tid >> 6, rest = tid & 63, ff = rest >> 1, eh = rest & 1;
    const int a = c & 1, bb = c >> 1;
    float out[16];

    if (!leftover) {
        if (side == 0) {
            float col[32];
            #pragma unroll
            for (int k = 0; k < 32; ++k) col[k] = sB[k * 64 + bb * 32 + ff];
            #pragma unroll
            for (int e0 = 0; e0 < 16; ++e0) {
                const int e = eh * 16 + e0; float acc = 0.f;
                #pragma unroll
                for (int k = 0; k < 32; ++k)
                    acc = fmaf(sA[e * 64 + a * 32 + k], col[k], acc);
                out[e0] = acc;
            }
        } else {
            float row[32];
            #pragma unroll
            for (int k = 0; k < 32; ++k) row[k] = sA[ff * 64 + a * 32 + k];
            #pragma unroll
            for (int e0 = 0; e0 < 16; ++e0) {
                const int e = eh * 16 + e0; float acc = 0.f;
                #pragma unroll
                for (int k = 0; k < 32; ++k)
                    acc = fmaf(row[k], sB[k * 64 + bb * 32 + e], acc);
                out[e0] = acc;
            }
        }
    } else {
        #pragma unroll
        for (int e0 = 0; e0 < 16; ++e0) {
            const int e = eh * 16 + e0;
            out[e0] = (side == 0) ? sA[e * 64 + a * 32 + ff]
                                  : sA[ff * 64 + a * 32 + e];
        }
    }

    float* Wt = Wbuf + ((size_t)stream * NPAIR + t) * SLICE;
    #pragma unroll
    for (int q0 = 0; q0 < 4; ++q0) {
        const int qq = eh * 4 + q0;
        float4 val = make_float4(out[q0 * 4 + 0], out[q0 * 4 + 1],
                                 out[q0 * 4 + 2], out[q0 * 4 + 3]);
        ((float4*)Wt)[(bb * 8 + qq) * 64 + a * 32 + ff] = val;
    }

    if (stream < 2 && tid < 64) {
        const int sd = stream;
        const float2* x2 = (const float2*)x;
        float2 xa, xb;
        if (!leftover) {
            int na, nb;
            if (sd == 0) { na = 2 * t + 1; nb = 2 * t + 2; }
            else         { int ma = 389 - 2 * t; na = HALF + ma; nb = na + 1; }
            xa = x2[(size_t)tid * N + na];
            xb = x2[(size_t)tid * N + nb];
        } else {
            xa = x2[(size_t)tid * N + (sd ? HALF : 391)];
            xb = make_float2(1.f, 0.f);
        }
        float4 w = make_float4(xa.x * xb.x, xa.y * xb.x, xa.x * xb.y, xa.y * xb.y);
        ((float4*)wtab)[((size_t)sd * 64 + tid) * NPAIR + t] = w;
    }
}

// ------ chain kernel: G=1, single-wave blocks, 4-slot LDS ring, no barriers ------
#define WAITV(n) do { \
    asm volatile("s_waitcnt vmcnt(" #n ")" ::: "memory"); \
    __builtin_amdgcn_sched_barrier(0); \
} while (0)

#define WAITL(n) do { \
    asm volatile("s_waitcnt lgkmcnt(" #n ")" ::: "memory"); \
    __builtin_amdgcn_sched_barrier(0); \
} while (0)

#define DSR(dst, OFF) \
    asm volatile("ds_read_b128 %0, %1 offset:%c2" \
                 : "=v"(dst) : "v"(sl_addr), "i"(OFF))

// stage slice (16 chunks x 1KB) into LDS slot SLOTD via global_load_lds.
// vmcnt-counted; LDS dest = wave-uniform base (+ lane*16 in hardware).
#define STAGE(SLOTD) do { \
    _Pragma("unroll") \
    for (int c_ = 0; c_ < 16; ++c_) { \
        __builtin_amdgcn_global_load_lds( \
            (const __attribute__((address_space(1))) uint32_t*)(gsrc + goff + c_ * 1024), \
            (__attribute__((address_space(3))) uint32_t*)(uintptr_t)((char*)lds_sl + (SLOTD) * 16384 + c_ * 1024), \
            16, 0, 0); \
    } \
    goff += 16384; \
} while (0)

// packed FMA quad: chunk pair (dl = chunk c, dh = chunk c+8), e = EB..EB+3
#define FMAQUAD(dl, dh, QAL, QAH, EB) do { \
    const f2 l0 = __builtin_shufflevector(dl, dl, 0, 1); \
    const f2 l1 = __builtin_shufflevector(dl, dl, 2, 3); \
    const f2 h0 = __builtin_shufflevector(dh, dh, 0, 1); \
    const f2 h1 = __builtin_shufflevector(dh, dh, 2, 3); \
    f2 sa0, sa1; \
    sa0.x = bcast(v0, EB + 0); sa0.y = bcast(v0, EB + 1); \
    QAL = __builtin_elementwise_fma(l0, sa0, QAL); \
    QAH = __builtin_elementwise_fma(h0, sa0, QAH); \
    sa1.x = bcast(v0, EB + 2); sa1.y = bcast(v0, EB + 3); \
    QAL = __builtin_elementwise_fma(l1, sa1, QAL); \
    QAH = __builtin_elementwise_fma(h1, sa1, QAH); \
} while (0)

// One step on slot SLOT (literal 0..3). WAITV(WN): slot's 16 gload_lds done.
// Issue 17 asm lgkm ops (w-pair + 16 b128 in consume order), stage slot+3,
// then lgkm ladder 12/8/4/0 (all <= 15: the r7 4-bit lesson).
#define STEP(SLOT, WN, DO_STAGE) do { \
    WAITV(WN); \
    f2 wa_; \
    asm volatile("ds_read2_b32 %0, %1 offset0:0 offset1:2" : "=v"(wa_) : "v"(w_addr)); \
    w_addr += 16; \
    f4 d0,d1,d2,d3,d4,d5,d6,d7,d8,d9,d10,d11,d12,d13,d14,d15; \
    DSR(d0, (SLOT)*16384 + 0);    DSR(d8,  (SLOT)*16384 + 8192); \
    DSR(d1, (SLOT)*16384 + 1024); DSR(d9,  (SLOT)*16384 + 9216); \
    DSR(d2, (SLOT)*16384 + 2048); DSR(d10, (SLOT)*16384 + 10240); \
    DSR(d3, (SLOT)*16384 + 3072); DSR(d11, (SLOT)*16384 + 11264); \
    DSR(d4, (SLOT)*16384 + 4096); DSR(d12, (SLOT)*16384 + 12288); \
    DSR(d5, (SLOT)*16384 + 5120); DSR(d13, (SLOT)*16384 + 13312); \
    DSR(d6, (SLOT)*16384 + 6144); DSR(d14, (SLOT)*16384 + 14336); \
    DSR(d7, (SLOT)*16384 + 7168); DSR(d15, (SLOT)*16384 + 15360); \
    if (DO_STAGE) { STAGE((SLOT + 3) & 3); } \
    f2 Q00 = {0.f,0.f}, Q01 = {0.f,0.f}, Q02 = {0.f,0.f}, Q03 = {0.f,0.f}; \
    WAITL(12); \
    FMAQUAD(d0, d8,  Q00, Q02, 0); \
    FMAQUAD(d1, d9,  Q00, Q02, 4); \
    WAITL(8); \
    FMAQUAD(d2, d10, Q00, Q02, 8); \
    FMAQUAD(d3, d11, Q00, Q02, 12); \
    WAITL(4); \
    FMAQUAD(d4, d12, Q01, Q03, 16); \
    FMAQUAD(d5, d13, Q01, Q03, 20); \
    WAITL(0); \
    FMAQUAD(d6, d14, Q01, Q03, 24); \
    FMAQUAD(d7, d15, Q01, Q03, 28); \
    const float q00 = Q00.x + Q00.y, q01 = Q01.x + Q01.y; \
    const float q02 = Q02.x + Q02.y, q03 = Q03.x + Q03.y; \
    const float part0 = fmaf(wa_.x, q00 + q01, wa_.y * (q02 + q03)); \
    v0 = part0 + __shfl_xor(part0, 32); \
} while (0)

// 512 blocks x 64 threads: 1 wave = ONE chain, no barriers (r22: barrier tax
// = +21us). LDS 4-slot ring -> 2-step lookahead (~1600cy > ~900cy HBM miss)
// WITHOUT touching the VGPR wall (r19: allocator caps reg rings at depth 2).
// 67KB LDS -> 2 blocks/CU = keeps r21's proven 2-wave TLP.
__global__ __launch_bounds__(64) void chain_kernel(
    const float* __restrict__ x,
    const float* __restrict__ A_first, const float* __restrict__ A_last,
    const float* __restrict__ Wbuf, const float* __restrict__ wtab,
    float* __restrict__ ws_v)
{
    __shared__ float  lds_sl[4 * SLICE];   // 64 KB ring
    __shared__ float4 lw[NPAIR + 2];       // weights per t

    const int lane = threadIdx.x, c2 = lane >> 5, f = lane & 31;
    const int blk = blockIdx.x, stream = blk & 7;
    const int side = stream >> 2, s = stream & 3;
    const int b = blk >> 3;               // 0..63

    // stage weights to LDS (coalesced reads from wtab[side][b][t])
    const float4* wt4 = (const float4*)wtab;
    for (int i = lane; i < NPAIR; i += 64)
        lw[i] = wt4[((size_t)side * 64 + b) * NPAIR + i];

    const float2* x2 = (const float2*)x;
    const int site0 = side ? (N - 1) : 0;
    const float2 af  = ((const float2*)(side ? A_last : A_first))[s * D + f];
    const float2 xx0 = x2[(size_t)b * N + site0];
    float v0 = fmaf(af.x, xx0.x, af.y * xx0.y);

    // drain all compiler-issued vmem/lds so counted waits below are exact
    asm volatile("s_waitcnt vmcnt(0) lgkmcnt(0)" ::: "memory");
    __builtin_amdgcn_sched_barrier(0);

    const char* gsrc = (const char*)Wbuf
                     + (size_t)stream * (NPAIR * SLICE) * 4 + (size_t)lane * 16;
    uint32_t goff = 0;
    uint32_t sl_addr = (uint32_t)(uintptr_t)&lds_sl[0] + (uint32_t)lane * 16;
    uint32_t w_addr  = (uint32_t)(uintptr_t)&lw[0] + (uint32_t)c2 * 4;

    // prologue: stage slots 0,1,2 (t = 0,1,2) -> 48 outstanding
    STAGE(0); STAGE(1); STAGE(2);

    for (int k = 0; k < 48; ++k) {        // t = 4k..4k+3, stages t+3
        STEP(0, 32, 1);
        STEP(1, 32, 1);
        STEP(2, 32, 1);
        STEP(3, 32, 1);
    }
    // k = 48: t = 192..195; t=192 stages slice 195 into slot 3
    STEP(0, 32, 1);
    STEP(1, 32, 0);
    STEP(2, 16, 0);
    STEP(3, 0,  0);

    if (lane < 32)
        ws_v[(side * S + s) * (B * D) + b * D + f] = v0;
}

// ---------------- fallback chain (round-1 style, used if ws too small) ----------------
__global__ __launch_bounds__(64) void chain_fb(
    const float* __restrict__ x, const float* __restrict__ A_first,
    const float* __restrict__ A_left, const float* __restrict__ A_right,
    const float* __restrict__ A_last, float* __restrict__ ws_v)
{
    const int blk = blockIdx.x, pair = blk & 7, b = blk >> 3;
    const int side = pair >> 2, s = pair & 3;
    const int lane = threadIdx.x, p = lane >> 5, j = lane & 31;
    const float* xb = x + b * (N * P);
    float v;
    if (side == 0) {
        v = fmaf(A_first[s*D*P + j*P + 0], xb[0], A_first[s*D*P + j*P + 1] * xb[1]);
        const float* Abase = A_left + (size_t)s * (NSTEP * D * P * D);
        for (int n = 1; n <= NSTEP; ++n) {
            const float* M = Abase + (n - 1) * (D * P * D) + p * D + j;
            const float x0 = xb[n*P], x1 = xb[n*P + 1];
            float t0 = 0.f, t1 = 0.f;
            #pragma unroll
            for (int i = 0; i < D; i += 2) {
                t0 = fmaf(bcast(v, i),     M[i * (P*D)],       t0);
                t1 = fmaf(bcast(v, i + 1), M[(i + 1) * (P*D)], t1);
            }
            const float t = t0 + t1, o = __shfl_xor(t, 32);
            v = (p == 0) ? fmaf(x0, t, x1 * o) : fmaf(x1, t, x0 * o);
        }
    } else {
        v = fmaf(A_last[s*D*P + j*P + 0], xb[(N-1)*P], A_last[s*D*P + j*P + 1] * xb[(N-1)*P + 1]);
        const float* Abase = A_right + (size_t)s * (NSTEP * D * P * D);
        for (int m = NSTEP - 1; m >= 0; --m) {
            const float4* R4 = (const float4*)(Abase + m * (D*P*D) + j * (P*D) + p * D);
            const float x0 = xb[(HALF+m)*P], x1 = xb[(HALF+m)*P + 1];
            float t0 = 0.f, t1 = 0.f;
            #pragma unroll
            for (int q = 0; q < 8; ++q) {
                const float4 rv = R4[q];
                t0 = fmaf(rv.x, bcast(v, 4*q+0), t0);
                t1 = fmaf(rv.y, bcast(v, 4*q+1), t1);
                t0 = fmaf(rv.z, bcast(v, 4*q+2), t0);
                t1 = fmaf(rv.w, bcast(v, 4*q+3), t1);
            }
            const float t = t0 + t1, o = __shfl_xor(t, 32);
            v = (p == 0) ? fmaf(x0, t, x1 * o) : fmaf(x1, t, x0 * o);
        }
    }
    if (p == 0) ws_v[(side*S + s)*(B*D) + b*D + j] = v;
}

// ---------------- fused label + product ----------------
__global__ __launch_bounds__(64) void label_prod_kernel(
    const float* __restrict__ ws_v, const float* __restrict__ A_label,
    float* __restrict__ out)
{
    const int b = blockIdx.x;
    const int lane = threadIdx.x, h = lane >> 5, j = lane & 31;
    float pr0 = 1.f, pr1 = 1.f, pr2 = 1.f, pr3 = 1.f, pr4 = 1.f;

    #pragma unroll
    for (int s = 0; s < S; ++s) {
        const float vj = ws_v[(0 * S + s) * (B * D) + b * D + j];
        const float rj = ws_v[(1 * S + s) * (B * D) + b * D + j];
        #pragma unroll
        for (int q = 0; q < 5; ++q) {
            const int l = h * 5 + q;
            float w = 0.f;
            #pragma unroll
            for (int d = 0; d < D; ++d)
                w = fmaf(bcast(vj, d), A_label[((s * D + d) * L + l) * D + j], w);
            float c = w * rj;
            c += __shfl_xor(c, 1); c += __shfl_xor(c, 2); c += __shfl_xor(c, 4);
            c += __shfl_xor(c, 8); c += __shfl_xor(c, 16);
            if (q == 0) pr0 *= c; else if (q == 1) pr1 *= c;
            else if (q == 2) pr2 *= c; else if (q == 3) pr3 *= c; else pr4 *= c;
        }
    }
    if (j == 0) {
        out[b * L + h * 5 + 0] = pr0;
        out[b * L + h * 5 + 1] = pr1;
        out[b * L + h * 5 + 2] = pr2;
        out[b * L + h * 5 + 3] = pr3;
        out[b * L + h * 5 + 4] = pr4;
    }
}

extern "C" void kernel_launch(void* const* d_in, const int* in_sizes, int n_in,
                              void* d_out, int out_size, void* d_ws, size_t ws_size,
                              hipStream_t stream) {
    const float* x       = (const float*)d_in[0];
    const float* A_first = (const float*)d_in[1];
    const float* A_left  = (const float*)d_in[2];
    const float* A_label = (const float*)d_in[3];
    const float* A_right = (const float*)d_in[4];
    const float* A_last  = (const float*)d_in[5];
    float* out = (float*)d_out;

    float* ws_v = (float*)d_ws;                       // 16384 floats
    float* wtab = ws_v + 2 * S * B * D;               // 2*64*196*4 = 100352 floats
    float* Wbuf = wtab + 2 * 64 * NPAIR * 4;          // 8*196*4096 = 6422528 floats
    const size_t need = (size_t)(16384 + 100352 + 8 * NPAIR * SLICE) * 4;

    if (ws_size >= need) {
        pair_kernel<<<dim3(8, NPAIR), dim3(256), 0, stream>>>(A_left, A_right, x, Wbuf, wtab);
        chain_kernel<<<dim3(512), dim3(64), 0, stream>>>(x, A_first, A_last, Wbuf, wtab, ws_v);
    } else {
        chain_fb<<<dim3(2 * S * B), dim3(64), 0, stream>>>(x, A_first, A_left, A_right, A_last, ws_v);
    }
    label_prod_kernel<<<dim3(B), dim3(64), 0, stream>>>(ws_v, A_label, out);
}

// Round 24
// 101.578 us; speedup vs baseline: 1.3147x; 1.3147x over previous
//
#include <hip/hip_runtime.h>
#include <stdint.h>

#define S 4
#define B 64
#define D 32
#define N 784
#define P 2
#define L 10
#define HALF 392
#define NSTEP 391
#define NPAIR 196              // 195 real pairs + 1 leftover single site
#define SLICE 4096             // floats per pair slice: 4 combos * 32*32 (16 KB)

typedef float f4 __attribute__((ext_vector_type(4)));
typedef float f2 __attribute__((ext_vector_type(2)));

__device__ __forceinline__ float bcast(float v, int lane) {
    return __uint_as_float(__builtin_amdgcn_readlane(__float_as_uint(v), lane));
}

// ---------------- precompute: pair matrices + weight table ----------------
// W layout (per stream,t): float4-chunk index (bb*8+qq)*64 + c2*32+f,
// chunk holds content[c = c2+2*bb][f][e = 4*qq + r].
// left:  content[c][f][e] = P_c[e][f];  right: content[c][f][e] = Q_c[f][e].
// wtab layout: [(side*64 + b)*NPAIR + t] (float4).
__global__ __launch_bounds__(256) void pair_kernel(
    const float* __restrict__ A_left, const float* __restrict__ A_right,
    const float* __restrict__ x,
    float* __restrict__ Wbuf, float* __restrict__ wtab)
{
    const int stream = blockIdx.x;      // 0..7
    const int t      = blockIdx.y;      // 0..195
    const int side   = stream >> 2, s = stream & 3;
    __shared__ float sA[2048], sB[2048];
    const int tid = threadIdx.x;
    const bool leftover = (t == 195);

    const float* As = (side ? A_right : A_left) + (size_t)s * (NSTEP * 2048);
    int ia, ib;
    if (side == 0) { ia = 2 * t; ib = 2 * t + 1; }
    else           { ia = 389 - 2 * t; ib = 390 - 2 * t; }
    if (leftover)  { ia = side ? 0 : 390; ib = ia; }

    const float4* ga = (const float4*)(As + (size_t)ia * 2048);
    const float4* gb = (const float4*)(As + (size_t)ib * 2048);
    ((float4*)sA)[tid] = ga[tid]; ((float4*)sA)[tid + 256] = ga[tid + 256];
    ((float4*)sB)[tid] = gb[tid]; ((float4*)sB)[tid + 256] = gb[tid + 256];
    __syncthreads();

    const int c = tid >> 6, rest = tid & 63, ff = rest >> 1, eh = rest & 1;
    const int a = c & 1, bb = c >> 1;
    float out[16];

    if (!leftover) {
        if (side == 0) {
            float col[32];
            #pragma unroll
            for (int k = 0; k < 32; ++k) col[k] = sB[k * 64 + bb * 32 + ff];
            #pragma unroll
            for (int e0 = 0; e0 < 16; ++e0) {
                const int e = eh * 16 + e0; float acc = 0.f;
                #pragma unroll
                for (int k = 0; k < 32; ++k)
                    acc = fmaf(sA[e * 64 + a * 32 + k], col[k], acc);
                out[e0] = acc;
            }
        } else {
            float row[32];
            #pragma unroll
            for (int k = 0; k < 32; ++k) row[k] = sA[ff * 64 + a * 32 + k];
            #pragma unroll
            for (int e0 = 0; e0 < 16; ++e0) {
                const int e = eh * 16 + e0; float acc = 0.f;
                #pragma unroll
                for (int k = 0; k < 32; ++k)
                    acc = fmaf(row[k], sB[k * 64 + bb * 32 + e], acc);
                out[e0] = acc;
            }
        }
    } else {
        #pragma unroll
        for (int e0 = 0; e0 < 16; ++e0) {
            const int e = eh * 16 + e0;
            out[e0] = (side == 0) ? sA[e * 64 + a * 32 + ff]
                                  : sA[ff * 64 + a * 32 + e];
        }
    }

    float* Wt = Wbuf + ((size_t)stream * NPAIR + t) * SLICE;
    #pragma unroll
    for (int q0 = 0; q0 < 4; ++q0) {
        const int qq = eh * 4 + q0;
        float4 val = make_float4(out[q0 * 4 + 0], out[q0 * 4 + 1],
                                 out[q0 * 4 + 2], out[q0 * 4 + 3]);
        ((float4*)Wt)[(bb * 8 + qq) * 64 + a * 32 + ff] = val;
    }

    if (stream < 2 && tid < 64) {
        const int sd = stream;
        const float2* x2 = (const float2*)x;
        float2 xa, xb;
        if (!leftover) {
            int na, nb;
            if (sd == 0) { na = 2 * t + 1; nb = 2 * t + 2; }
            else         { int ma = 389 - 2 * t; na = HALF + ma; nb = na + 1; }
            xa = x2[(size_t)tid * N + na];
            xb = x2[(size_t)tid * N + nb];
        } else {
            xa = x2[(size_t)tid * N + (sd ? HALF : 391)];
            xb = make_float2(1.f, 0.f);
        }
        float4 w = make_float4(xa.x * xb.x, xa.y * xb.x, xa.x * xb.y, xa.y * xb.y);
        ((float4*)wtab)[((size_t)sd * 64 + tid) * NPAIR + t] = w;
    }
}

// ------ chain kernel: G=1, 512 blocks (2 waves/CU), quarter-split waits ------
#define GLOADX4(dst, voff, base, off) \
    asm volatile("global_load_dwordx4 %0, %1, %2 offset:" #off \
                 : "=v"(dst) : "v"(voff), "s"(base))

// Issue in CONSUME order (FMAQUAD q uses SLq & SL8+q) so quarter-waits
// release exactly the next 2 FMAQUADs' inputs.
#define ISSUE_SLOT(SL) do { \
    GLOADX4(SL##0,  voff, base0, 0);    GLOADX4(SL##8,  voff, base2, 0); \
    GLOADX4(SL##1,  voff, base0, 1024); GLOADX4(SL##9,  voff, base2, 1024); \
    GLOADX4(SL##2,  voff, base0, 2048); GLOADX4(SL##10, voff, base2, 2048); \
    GLOADX4(SL##3,  voff, base0, 3072); GLOADX4(SL##11, voff, base2, 3072); \
    GLOADX4(SL##4,  voff, base1, 0);    GLOADX4(SL##12, voff, base3, 0); \
    GLOADX4(SL##5,  voff, base1, 1024); GLOADX4(SL##13, voff, base3, 1024); \
    GLOADX4(SL##6,  voff, base1, 2048); GLOADX4(SL##14, voff, base3, 2048); \
    GLOADX4(SL##7,  voff, base1, 3072); GLOADX4(SL##15, voff, base3, 3072); \
    voff += 16384; \
} while (0)

#define WAIT(n) do { \
    asm volatile("s_waitcnt vmcnt(" #n ")"); \
    __builtin_amdgcn_sched_barrier(0); \
} while (0)

// Single-chain packed FMA quad: e = EB..EB+3 against one v register.
#define FMAQUAD(SLl, SLh, QAL, QAH, EB) do { \
    const f2 l0 = __builtin_shufflevector(SLl, SLl, 0, 1); \
    const f2 l1 = __builtin_shufflevector(SLl, SLl, 2, 3); \
    const f2 h0 = __builtin_shufflevector(SLh, SLh, 0, 1); \
    const f2 h1 = __builtin_shufflevector(SLh, SLh, 2, 3); \
    f2 sa0, sa1; \
    sa0.x = bcast(v0, EB + 0); sa0.y = bcast(v0, EB + 1); \
    QAL = __builtin_elementwise_fma(l0, sa0, QAL); \
    QAH = __builtin_elementwise_fma(h0, sa0, QAH); \
    sa1.x = bcast(v0, EB + 2); sa1.y = bcast(v0, EB + 3); \
    QAL = __builtin_elementwise_fma(l1, sa1, QAL); \
    QAH = __builtin_elementwise_fma(h1, sa1, QAH); \
} while (0)

// Consume with quarter-waits WQ1..WQ4 (release 4 loads each, retire order).
#define CONSUME_SLOT(SL, W0, WQ1, WQ2, WQ3, WQ4) do { \
    f2 Q00 = {0.f, 0.f}, Q01 = {0.f, 0.f}, Q02 = {0.f, 0.f}, Q03 = {0.f, 0.f}; \
    WAIT(WQ1); \
    FMAQUAD(SL##0, SL##8,  Q00, Q02, 0); \
    FMAQUAD(SL##1, SL##9,  Q00, Q02, 4); \
    WAIT(WQ2); \
    FMAQUAD(SL##2, SL##10, Q00, Q02, 8); \
    FMAQUAD(SL##3, SL##11, Q00, Q02, 12); \
    WAIT(WQ3); \
    FMAQUAD(SL##4, SL##12, Q01, Q03, 16); \
    FMAQUAD(SL##5, SL##13, Q01, Q03, 20); \
    WAIT(WQ4); \
    FMAQUAD(SL##6, SL##14, Q01, Q03, 24); \
    FMAQUAD(SL##7, SL##15, Q01, Q03, 28); \
    const float q00 = Q00.x + Q00.y, q01 = Q01.x + Q01.y; \
    const float q02 = Q02.x + Q02.y, q03 = Q03.x + Q03.y; \
    const float wl0 = c2 ? W0.y : W0.x, wh0 = c2 ? W0.w : W0.z; \
    const float part0 = fmaf(wl0, q00 + q01, wh0 * (q02 + q03)); \
    v0 = part0 + __shfl_xor(part0, 32); \
} while (0)

// 512 blocks x 64 threads: 1 wave = ONE chain; 2 independent waves/CU (r21
// champion structure). Added: quarter-split waits so each quarter's L2
// delivery overlaps the previous quarter's FMAs -- at 2 waves/CU the two
// waves contend for delivery, so finer waits give the scheduler room.
__global__ __attribute__((amdgpu_waves_per_eu(2, 2))) __launch_bounds__(64, 2)
void chain_kernel(
    const float* __restrict__ x,
    const float* __restrict__ A_first, const float* __restrict__ A_last,
    const float* __restrict__ Wbuf, const float* __restrict__ wtab,
    float* __restrict__ ws_v)
{
    __shared__ float4 lw[NPAIR];   // weights for this wave's chain

    const int lane = threadIdx.x, c2 = lane >> 5, f = lane & 31;
    const int blk = blockIdx.x, stream = blk & 7;
    const int side = stream >> 2, s = stream & 3;
    const int b = blk >> 3;               // 0..63

    // stage weights to LDS (coalesced reads from wtab[side][b][t])
    const float4* wt4 = (const float4*)wtab;
    for (int i = lane; i < NPAIR; i += 64)
        lw[i] = wt4[((size_t)side * 64 + b) * NPAIR + i];

    const float2* x2 = (const float2*)x;
    const int site0 = side ? (N - 1) : 0;
    const float2 af  = ((const float2*)(side ? A_last : A_first))[s * D + f];
    const float2 xx0 = x2[(size_t)b * N + site0];
    float v0 = fmaf(af.x, xx0.x, af.y * xx0.y);

    const uint64_t wbase = (uint64_t)((const char*)Wbuf
                         + (size_t)stream * (NPAIR * SLICE) * 4);
    const uint64_t base0 = wbase, base1 = wbase + 4096;
    const uint64_t base2 = wbase + 8192, base3 = wbase + 12288;
    uint32_t voff = (uint32_t)lane * 16;

    f4 KA0,KA1,KA2,KA3,KA4,KA5,KA6,KA7,KA8,KA9,KA10,KA11,KA12,KA13,KA14,KA15;
    f4 KB0,KB1,KB2,KB3,KB4,KB5,KB6,KB7,KB8,KB9,KB10,KB11,KB12,KB13,KB14,KB15;

    ISSUE_SLOT(KA);   // slice 0
    ISSUE_SLOT(KB);   // slice 1
    float4 wA0 = lw[0];                   // weights for t=0
    float4 wB0 = lw[1];                   // weights for t=1

    for (int k = 0; k < 97; ++k) {        // consumes t = 0..193, issues 2..195
        CONSUME_SLOT(KA, wA0, 28, 24, 20, 16);  // t = 2k
        ISSUE_SLOT(KA);                         // slice 2k+2
        wA0 = lw[2 * k + 2];
        CONSUME_SLOT(KB, wB0, 28, 24, 20, 16);  // t = 2k+1
        ISSUE_SLOT(KB);                         // slice 2k+3
        wB0 = lw[2 * k + 3];
    }
    CONSUME_SLOT(KA, wA0, 28, 24, 20, 16);      // t = 194 (KB in flight)
    CONSUME_SLOT(KB, wB0, 12, 8, 4, 0);         // t = 195

    if (lane < 32)
        ws_v[(side * S + s) * (B * D) + b * D + f] = v0;
}

// ---------------- fallback chain (round-1 style, used if ws too small) ----------------
__global__ __launch_bounds__(64) void chain_fb(
    const float* __restrict__ x, const float* __restrict__ A_first,
    const float* __restrict__ A_left, const float* __restrict__ A_right,
    const float* __restrict__ A_last, float* __restrict__ ws_v)
{
    const int blk = blockIdx.x, pair = blk & 7, b = blk >> 3;
    const int side = pair >> 2, s = pair & 3;
    const int lane = threadIdx.x, p = lane >> 5, j = lane & 31;
    const float* xb = x + b * (N * P);
    float v;
    if (side == 0) {
        v = fmaf(A_first[s*D*P + j*P + 0], xb[0], A_first[s*D*P + j*P + 1] * xb[1]);
        const float* Abase = A_left + (size_t)s * (NSTEP * D * P * D);
        for (int n = 1; n <= NSTEP; ++n) {
            const float* M = Abase + (n - 1) * (D * P * D) + p * D + j;
            const float x0 = xb[n*P], x1 = xb[n*P + 1];
            float t0 = 0.f, t1 = 0.f;
            #pragma unroll
            for (int i = 0; i < D; i += 2) {
                t0 = fmaf(bcast(v, i),     M[i * (P*D)],       t0);
                t1 = fmaf(bcast(v, i + 1), M[(i + 1) * (P*D)], t1);
            }
            const float t = t0 + t1, o = __shfl_xor(t, 32);
            v = (p == 0) ? fmaf(x0, t, x1 * o) : fmaf(x1, t, x0 * o);
        }
    } else {
        v = fmaf(A_last[s*D*P + j*P + 0], xb[(N-1)*P], A_last[s*D*P + j*P + 1] * xb[(N-1)*P + 1]);
        const float* Abase = A_right + (size_t)s * (NSTEP * D * P * D);
        for (int m = NSTEP - 1; m >= 0; --m) {
            const float4* R4 = (const float4*)(Abase + m * (D*P*D) + j * (P*D) + p * D);
            const float x0 = xb[(HALF+m)*P], x1 = xb[(HALF+m)*P + 1];
            float t0 = 0.f, t1 = 0.f;
            #pragma unroll
            for (int q = 0; q < 8; ++q) {
                const float4 rv = R4[q];
                t0 = fmaf(rv.x, bcast(v, 4*q+0), t0);
                t1 = fmaf(rv.y, bcast(v, 4*q+1), t1);
                t0 = fmaf(rv.z, bcast(v, 4*q+2), t0);
                t1 = fmaf(rv.w, bcast(v, 4*q+3), t1);
            }
            const float t = t0 + t1, o = __shfl_xor(t, 32);
            v = (p == 0) ? fmaf(x0, t, x1 * o) : fmaf(x1, t, x0 * o);
        }
    }
    if (p == 0) ws_v[(side*S + s)*(B*D) + b*D + j] = v;
}

// ---------------- fused label + product ----------------
__global__ __launch_bounds__(64) void label_prod_kernel(
    const float* __restrict__ ws_v, const float* __restrict__ A_label,
    float* __restrict__ out)
{
    const int b = blockIdx.x;
    const int lane = threadIdx.x, h = lane >> 5, j = lane & 31;
    float pr0 = 1.f, pr1 = 1.f, pr2 = 1.f, pr3 = 1.f, pr4 = 1.f;

    #pragma unroll
    for (int s = 0; s < S; ++s) {
        const float vj = ws_v[(0 * S + s) * (B * D) + b * D + j];
        const float rj = ws_v[(1 * S + s) * (B * D) + b * D + j];
        #pragma unroll
        for (int q = 0; q < 5; ++q) {
            const int l = h * 5 + q;
            float w = 0.f;
            #pragma unroll
            for (int d = 0; d < D; ++d)
                w = fmaf(bcast(vj, d), A_label[((s * D + d) * L + l) * D + j], w);
            float c = w * rj;
            c += __shfl_xor(c, 1); c += __shfl_xor(c, 2); c += __shfl_xor(c, 4);
            c += __shfl_xor(c, 8); c += __shfl_xor(c, 16);
            if (q == 0) pr0 *= c; else if (q == 1) pr1 *= c;
            else if (q == 2) pr2 *= c; else if (q == 3) pr3 *= c; else pr4 *= c;
        }
    }
    if (j == 0) {
        out[b * L + h * 5 + 0] = pr0;
        out[b * L + h * 5 + 1] = pr1;
        out[b * L + h * 5 + 2] = pr2;
        out[b * L + h * 5 + 3] = pr3;
        out[b * L + h * 5 + 4] = pr4;
    }
}

extern "C" void kernel_launch(void* const* d_in, const int* in_sizes, int n_in,
                              void* d_out, int out_size, void* d_ws, size_t ws_size,
                              hipStream_t stream) {
    const float* x       = (const float*)d_in[0];
    const float* A_first = (const float*)d_in[1];
    const float* A_left  = (const float*)d_in[2];
    const float* A_label = (const float*)d_in[3];
    const float* A_right = (const float*)d_in[4];
    const float* A_last  = (const float*)d_in[5];
    float* out = (float*)d_out;

    float* ws_v = (float*)d_ws;                       // 16384 floats
    float* wtab = ws_v + 2 * S * B * D;               // 2*64*196*4 = 100352 floats
    float* Wbuf = wtab + 2 * 64 * NPAIR * 4;          // 8*196*4096 = 6422528 floats
    const size_t need = (size_t)(16384 + 100352 + 8 * NPAIR * SLICE) * 4;

    if (ws_size >= need) {
        pair_kernel<<<dim3(8, NPAIR), dim3(256), 0, stream>>>(A_left, A_right, x, Wbuf, wtab);
        chain_kernel<<<dim3(512), dim3(64), 0, stream>>>(x, A_first, A_last, Wbuf, wtab, ws_v);
    } else {
        chain_fb<<<dim3(2 * S * B), dim3(64), 0, stream>>>(x, A_first, A_left, A_right, A_last, ws_v);
    }
    label_prod_kernel<<<dim3(B), dim3(64), 0, stream>>>(ws_v, A_label, out);
}

// Round 25
// 99.130 us; speedup vs baseline: 1.3472x; 1.0247x over previous
//
#include <hip/hip_runtime.h>
#include <stdint.h>

#define S 4
#define B 64
#define D 32
#define N 784
#define P 2
#define L 10
#define HALF 392
#define NSTEP 391
#define NPAIR 196              // 195 real pairs + 1 leftover single site
#define SLICE 4096             // floats per pair slice: 4 combos * 32*32 (16 KB)

typedef float f4 __attribute__((ext_vector_type(4)));
typedef float f2 __attribute__((ext_vector_type(2)));

__device__ __forceinline__ float bcast(float v, int lane) {
    return __uint_as_float(__builtin_amdgcn_readlane(__float_as_uint(v), lane));
}

// ---------------- precompute: pair matrices + weight table ----------------
// W layout (per stream,t): float4-chunk index (bb*8+qq)*64 + lane, lane = c2*32+f,
// chunk holds content[c = c2+2*bb][f][e = 4*qq + r].
// left:  content[c][f][e] = P_c[e][f];  right: content[c][f][e] = Q_c[f][e].
// wtab layout: [(side*64 + b)*NPAIR + t] (float4).
__global__ __launch_bounds__(256) void pair_kernel(
    const float* __restrict__ A_left, const float* __restrict__ A_right,
    const float* __restrict__ x,
    float* __restrict__ Wbuf, float* __restrict__ wtab)
{
    const int stream = blockIdx.x;      // 0..7 -> linear_id % 8 == stream (XCD pin)
    const int t      = blockIdx.y;      // 0..195
    const int side   = stream >> 2, s = stream & 3;
    __shared__ float sA[2048], sB[2048];
    const int tid = threadIdx.x;
    const bool leftover = (t == 195);

    const float* As = (side ? A_right : A_left) + (size_t)s * (NSTEP * 2048);
    int ia, ib;
    if (side == 0) { ia = 2 * t; ib = 2 * t + 1; }
    else           { ia = 389 - 2 * t; ib = 390 - 2 * t; }
    if (leftover)  { ia = side ? 0 : 390; ib = ia; }

    const float4* ga = (const float4*)(As + (size_t)ia * 2048);
    const float4* gb = (const float4*)(As + (size_t)ib * 2048);
    ((float4*)sA)[tid] = ga[tid]; ((float4*)sA)[tid + 256] = ga[tid + 256];
    ((float4*)sB)[tid] = gb[tid]; ((float4*)sB)[tid + 256] = gb[tid + 256];
    __syncthreads();

    const int c = tid >> 6, rest = tid & 63, ff = rest >> 1, eh = rest & 1;
    const int a = c & 1, bb = c >> 1;
    float out[16];

    if (!leftover) {
        if (side == 0) {
            float col[32];
            #pragma unroll
            for (int k = 0; k < 32; ++k) col[k] = sB[k * 64 + bb * 32 + ff];
            #pragma unroll
            for (int e0 = 0; e0 < 16; ++e0) {
                const int e = eh * 16 + e0; float acc = 0.f;
                #pragma unroll
                for (int k = 0; k < 32; ++k)
                    acc = fmaf(sA[e * 64 + a * 32 + k], col[k], acc);
                out[e0] = acc;
            }
        } else {
            float row[32];
            #pragma unroll
            for (int k = 0; k < 32; ++k) row[k] = sA[ff * 64 + a * 32 + k];
            #pragma unroll
            for (int e0 = 0; e0 < 16; ++e0) {
                const int e = eh * 16 + e0; float acc = 0.f;
                #pragma unroll
                for (int k = 0; k < 32; ++k)
                    acc = fmaf(row[k], sB[k * 64 + bb * 32 + e], acc);
                out[e0] = acc;
            }
        }
    } else {
        #pragma unroll
        for (int e0 = 0; e0 < 16; ++e0) {
            const int e = eh * 16 + e0;
            out[e0] = (side == 0) ? sA[e * 64 + a * 32 + ff]
                                  : sA[ff * 64 + a * 32 + e];
        }
    }

    float* Wt = Wbuf + ((size_t)stream * NPAIR + t) * SLICE;
    #pragma unroll
    for (int q0 = 0; q0 < 4; ++q0) {
        const int qq = eh * 4 + q0;
        float4 val = make_float4(out[q0 * 4 + 0], out[q0 * 4 + 1],
                                 out[q0 * 4 + 2], out[q0 * 4 + 3]);
        ((float4*)Wt)[(bb * 8 + qq) * 64 + a * 32 + ff] = val;
    }

    if (stream < 2 && tid < 64) {
        const int sd = stream;
        const float2* x2 = (const float2*)x;
        float2 xa, xb;
        if (!leftover) {
            int na, nb;
            if (sd == 0) { na = 2 * t + 1; nb = 2 * t + 2; }
            else         { int ma = 389 - 2 * t; na = HALF + ma; nb = na + 1; }
            xa = x2[(size_t)tid * N + na];
            xb = x2[(size_t)tid * N + nb];
        } else {
            xa = x2[(size_t)tid * N + (sd ? HALF : 391)];
            xb = make_float2(1.f, 0.f);
        }
        float4 w = make_float4(xa.x * xb.x, xa.y * xb.x, xa.x * xb.y, xa.y * xb.y);
        ((float4*)wtab)[((size_t)sd * 64 + tid) * NPAIR + t] = w;
    }
}

// ---------------- chain kernel: G=1, 512 blocks (2 waves/CU TLP) ----------------
#define GLOADX4(dst, voff, base, off) \
    asm volatile("global_load_dwordx4 %0, %1, %2 offset:" #off \
                 : "=v"(dst) : "v"(voff), "s"(base))

#define ISSUE_SLOT(SL) do { \
    GLOADX4(SL##0,  voff, base0, 0); GLOADX4(SL##1,  voff, base0, 1024); \
    GLOADX4(SL##2,  voff, base0, 2048); GLOADX4(SL##3,  voff, base0, 3072); \
    GLOADX4(SL##4,  voff, base1, 0); GLOADX4(SL##5,  voff, base1, 1024); \
    GLOADX4(SL##6,  voff, base1, 2048); GLOADX4(SL##7,  voff, base1, 3072); \
    GLOADX4(SL##8,  voff, base2, 0); GLOADX4(SL##9,  voff, base2, 1024); \
    GLOADX4(SL##10, voff, base2, 2048); GLOADX4(SL##11, voff, base2, 3072); \
    GLOADX4(SL##12, voff, base3, 0); GLOADX4(SL##13, voff, base3, 1024); \
    GLOADX4(SL##14, voff, base3, 2048); GLOADX4(SL##15, voff, base3, 3072); \
    voff += 16384; \
} while (0)

#define WAIT(n) do { \
    asm volatile("s_waitcnt vmcnt(" #n ")"); \
    __builtin_amdgcn_sched_barrier(0); \
} while (0)

// Single-chain packed FMA quad: e = EB..EB+3 against one v register.
#define FMAQUAD(SLl, SLh, QAL, QAH, EB) do { \
    const f2 l0 = __builtin_shufflevector(SLl, SLl, 0, 1); \
    const f2 l1 = __builtin_shufflevector(SLl, SLl, 2, 3); \
    const f2 h0 = __builtin_shufflevector(SLh, SLh, 0, 1); \
    const f2 h1 = __builtin_shufflevector(SLh, SLh, 2, 3); \
    f2 sa0, sa1; \
    sa0.x = bcast(v0, EB + 0); sa0.y = bcast(v0, EB + 1); \
    QAL = __builtin_elementwise_fma(l0, sa0, QAL); \
    QAH = __builtin_elementwise_fma(h0, sa0, QAH); \
    sa1.x = bcast(v0, EB + 2); sa1.y = bcast(v0, EB + 3); \
    QAL = __builtin_elementwise_fma(l1, sa1, QAL); \
    QAH = __builtin_elementwise_fma(h1, sa1, QAH); \
} while (0)

#define CONSUME_SLOT(SL, W0) do { \
    f2 Q00 = {0.f, 0.f}, Q01 = {0.f, 0.f}, Q02 = {0.f, 0.f}, Q03 = {0.f, 0.f}; \
    FMAQUAD(SL##0, SL##8,  Q00, Q02, 0); \
    FMAQUAD(SL##1, SL##9,  Q00, Q02, 4); \
    FMAQUAD(SL##2, SL##10, Q00, Q02, 8); \
    FMAQUAD(SL##3, SL##11, Q00, Q02, 12); \
    FMAQUAD(SL##4, SL##12, Q01, Q03, 16); \
    FMAQUAD(SL##5, SL##13, Q01, Q03, 20); \
    FMAQUAD(SL##6, SL##14, Q01, Q03, 24); \
    FMAQUAD(SL##7, SL##15, Q01, Q03, 28); \
    const float q00 = Q00.x + Q00.y, q01 = Q01.x + Q01.y; \
    const float q02 = Q02.x + Q02.y, q03 = Q03.x + Q03.y; \
    const float wl0 = c2 ? W0.y : W0.x, wh0 = c2 ? W0.w : W0.z; \
    const float part0 = fmaf(wl0, q00 + q01, wh0 * (q02 + q03)); \
    v0 = part0 + __shfl_xor(part0, 32); \
} while (0)

// 512 blocks x 64 threads: 1 wave = ONE chain; 2 independent waves/CU.
// CHAMPION (r21, 99.5us total / 63.7us chain): TLP is the lever -- while
// wave A stalls on vmcnt, wave B issues. Further levers all measured dead:
// reg-ring depth>2 (allocator cap, r19), LDS ring (r8/r23), barrier-coupled
// wave splits (r22: +21us), prefetch warming (r16), split waits (r20/r24).
// Chain register-ingress ~25 TB/s ~= 73% of L2 aggregate with a serial
// dependency chain -- the practical floor for this structure.
__global__ __attribute__((amdgpu_waves_per_eu(2, 2))) __launch_bounds__(64, 2)
void chain_kernel(
    const float* __restrict__ x,
    const float* __restrict__ A_first, const float* __restrict__ A_last,
    const float* __restrict__ Wbuf, const float* __restrict__ wtab,
    float* __restrict__ ws_v)
{
    __shared__ float4 lw[NPAIR];   // weights for this wave's chain

    const int lane = threadIdx.x, c2 = lane >> 5, f = lane & 31;
    const int blk = blockIdx.x, stream = blk & 7;
    const int side = stream >> 2, s = stream & 3;
    const int b = blk >> 3;               // 0..63

    // stage weights to LDS (coalesced reads from wtab[side][b][t])
    const float4* wt4 = (const float4*)wtab;
    for (int i = lane; i < NPAIR; i += 64)
        lw[i] = wt4[((size_t)side * 64 + b) * NPAIR + i];

    const float2* x2 = (const float2*)x;
    const int site0 = side ? (N - 1) : 0;
    const float2 af  = ((const float2*)(side ? A_last : A_first))[s * D + f];
    const float2 xx0 = x2[(size_t)b * N + site0];
    float v0 = fmaf(af.x, xx0.x, af.y * xx0.y);

    const uint64_t wbase = (uint64_t)((const char*)Wbuf
                         + (size_t)stream * (NPAIR * SLICE) * 4);
    const uint64_t base0 = wbase, base1 = wbase + 4096;
    const uint64_t base2 = wbase + 8192, base3 = wbase + 12288;
    uint32_t voff = (uint32_t)lane * 16;

    f4 KA0,KA1,KA2,KA3,KA4,KA5,KA6,KA7,KA8,KA9,KA10,KA11,KA12,KA13,KA14,KA15;
    f4 KB0,KB1,KB2,KB3,KB4,KB5,KB6,KB7,KB8,KB9,KB10,KB11,KB12,KB13,KB14,KB15;

    ISSUE_SLOT(KA);   // slice 0
    ISSUE_SLOT(KB);   // slice 1
    float4 wA0 = lw[0];                   // weights for t=0
    float4 wB0 = lw[1];                   // weights for t=1

    for (int k = 0; k < 97; ++k) {        // consumes t = 0..193, issues 2..195
        WAIT(16); CONSUME_SLOT(KA, wA0);  // t = 2k
        ISSUE_SLOT(KA);                   // slice 2k+2
        wA0 = lw[2 * k + 2];
        WAIT(16); CONSUME_SLOT(KB, wB0);  // t = 2k+1
        ISSUE_SLOT(KB);                   // slice 2k+3
        wB0 = lw[2 * k + 3];
    }
    WAIT(16); CONSUME_SLOT(KA, wA0);      // t = 194
    WAIT(0);  CONSUME_SLOT(KB, wB0);      // t = 195

    if (lane < 32)
        ws_v[(side * S + s) * (B * D) + b * D + f] = v0;
}

// ---------------- fallback chain (round-1 style, used if ws too small) ----------------
__global__ __launch_bounds__(64) void chain_fb(
    const float* __restrict__ x, const float* __restrict__ A_first,
    const float* __restrict__ A_left, const float* __restrict__ A_right,
    const float* __restrict__ A_last, float* __restrict__ ws_v)
{
    const int blk = blockIdx.x, pair = blk & 7, b = blk >> 3;
    const int side = pair >> 2, s = pair & 3;
    const int lane = threadIdx.x, p = lane >> 5, j = lane & 31;
    const float* xb = x + b * (N * P);
    float v;
    if (side == 0) {
        v = fmaf(A_first[s*D*P + j*P + 0], xb[0], A_first[s*D*P + j*P + 1] * xb[1]);
        const float* Abase = A_left + (size_t)s * (NSTEP * D * P * D);
        for (int n = 1; n <= NSTEP; ++n) {
            const float* M = Abase + (n - 1) * (D * P * D) + p * D + j;
            const float x0 = xb[n*P], x1 = xb[n*P + 1];
            float t0 = 0.f, t1 = 0.f;
            #pragma unroll
            for (int i = 0; i < D; i += 2) {
                t0 = fmaf(bcast(v, i),     M[i * (P*D)],       t0);
                t1 = fmaf(bcast(v, i + 1), M[(i + 1) * (P*D)], t1);
            }
            const float t = t0 + t1, o = __shfl_xor(t, 32);
            v = (p == 0) ? fmaf(x0, t, x1 * o) : fmaf(x1, t, x0 * o);
        }
    } else {
        v = fmaf(A_last[s*D*P + j*P + 0], xb[(N-1)*P], A_last[s*D*P + j*P + 1] * xb[(N-1)*P + 1]);
        const float* Abase = A_right + (size_t)s * (NSTEP * D * P * D);
        for (int m = NSTEP - 1; m >= 0; --m) {
            const float4* R4 = (const float4*)(Abase + m * (D*P*D) + j * (P*D) + p * D);
            const float x0 = xb[(HALF+m)*P], x1 = xb[(HALF+m)*P + 1];
            float t0 = 0.f, t1 = 0.f;
            #pragma unroll
            for (int q = 0; q < 8; ++q) {
                const float4 rv = R4[q];
                t0 = fmaf(rv.x, bcast(v, 4*q+0), t0);
                t1 = fmaf(rv.y, bcast(v, 4*q+1), t1);
                t0 = fmaf(rv.z, bcast(v, 4*q+2), t0);
                t1 = fmaf(rv.w, bcast(v, 4*q+3), t1);
            }
            const float t = t0 + t1, o = __shfl_xor(t, 32);
            v = (p == 0) ? fmaf(x0, t, x1 * o) : fmaf(x1, t, x0 * o);
        }
    }
    if (p == 0) ws_v[(side*S + s)*(B*D) + b*D + j] = v;
}

// ---------------- fused label + product ----------------
__global__ __launch_bounds__(64) void label_prod_kernel(
    const float* __restrict__ ws_v, const float* __restrict__ A_label,
    float* __restrict__ out)
{
    const int b = blockIdx.x;
    const int lane = threadIdx.x, h = lane >> 5, j = lane & 31;
    float pr0 = 1.f, pr1 = 1.f, pr2 = 1.f, pr3 = 1.f, pr4 = 1.f;

    #pragma unroll
    for (int s = 0; s < S; ++s) {
        const float vj = ws_v[(0 * S + s) * (B * D) + b * D + j];
        const float rj = ws_v[(1 * S + s) * (B * D) + b * D + j];
        #pragma unroll
        for (int q = 0; q < 5; ++q) {
            const int l = h * 5 + q;
            float w = 0.f;
            #pragma unroll
            for (int d = 0; d < D; ++d)
                w = fmaf(bcast(vj, d), A_label[((s * D + d) * L + l) * D + j], w);
            float c = w * rj;
            c += __shfl_xor(c, 1); c += __shfl_xor(c, 2); c += __shfl_xor(c, 4);
            c += __shfl_xor(c, 8); c += __shfl_xor(c, 16);
            if (q == 0) pr0 *= c; else if (q == 1) pr1 *= c;
            else if (q == 2) pr2 *= c; else if (q == 3) pr3 *= c; else pr4 *= c;
        }
    }
    if (j == 0) {
        out[b * L + h * 5 + 0] = pr0;
        out[b * L + h * 5 + 1] = pr1;
        out[b * L + h * 5 + 2] = pr2;
        out[b * L + h * 5 + 3] = pr3;
        out[b * L + h * 5 + 4] = pr4;
    }
}

extern "C" void kernel_launch(void* const* d_in, const int* in_sizes, int n_in,
                              void* d_out, int out_size, void* d_ws, size_t ws_size,
                              hipStream_t stream) {
    const float* x       = (const float*)d_in[0];
    const float* A_first = (const float*)d_in[1];
    const float* A_left  = (const float*)d_in[2];
    const float* A_label = (const float*)d_in[3];
    const float* A_right = (const float*)d_in[4];
    const float* A_last  = (const float*)d_in[5];
    float* out = (float*)d_out;

    float* ws_v = (float*)d_ws;                       // 16384 floats
    float* wtab = ws_v + 2 * S * B * D;               // 2*64*196*4 = 100352 floats
    float* Wbuf = wtab + 2 * 64 * NPAIR * 4;          // 8*196*4096 = 6422528 floats
    const size_t need = (size_t)(16384 + 100352 + 8 * NPAIR * SLICE) * 4;

    if (ws_size >= need) {
        pair_kernel<<<dim3(8, NPAIR), dim3(256), 0, stream>>>(A_left, A_right, x, Wbuf, wtab);
        chain_kernel<<<dim3(512), dim3(64), 0, stream>>>(x, A_first, A_last, Wbuf, wtab, ws_v);
    } else {
        chain_fb<<<dim3(2 * S * B), dim3(64), 0, stream>>>(x, A_first, A_left, A_right, A_last, ws_v);
    }
    label_prod_kernel<<<dim3(B), dim3(64), 0, stream>>>(ws_v, A_label, out);
}